// Round 4
// baseline (212.540 us; speedup 1.0000x reference)
//
#include <hip/hip_runtime.h>
#include <math.h>

// Problem constants
#define SEQ   4096
#define DIM   512
#define BW    24            // band half-width: prior underflows fp32 beyond |i-j|~20
#define NDIAG 49            // 2*BW+1
#define VSTR  4608          // padded row stride for band/vectors (4096 + 512)
#define VOFF  256           // data offset inside padded row (zeros on both sides)
#define INV_N (1.0f/4096.0f)

// ws layout in floats
#define OFF_KB   0                          // K band, 2 groups x 49 x VSTR
#define SZ_BAND  (2*NDIAG*VSTR)             // 451584
#define OFF_DB   (OFF_KB + SZ_BAND)         // dist band (NOT zeroed: always gated by Kb==0)
#define OFF_VEC  (OFF_DB + SZ_BAND)         // 6 padded vectors: u(g0,g1), y(g0,g1), v(g0,g1)
#define SZ_VEC   (6*VSTR)
#define OFF_PX   (OFF_VEC + SZ_VEC)         // pMp for P,Q,R,S : 4 x 4096
#define SZ_PX    (4*SEQ)
#define OFF_SC   (OFF_PX + SZ_PX)           // scalars: [0,1]=crit g0/g1, [2,3]=S g0/g1
#define SZ_SC    16
#define OFF_BBF  (OFF_SC + SZ_SC)           // Bsym bf16 512x512
#define SZ_BBF   (DIM*DIM/2)
#define OFF_QBF  (OFF_BBF + SZ_BBF)         // Q,S bf16 2x4096x512
#define SZ_QBF   (2*SEQ*DIM/2)
#define OFF_GBF  (OFF_QBF + SZ_QBF)         // P@B, R@B bf16
#define SZ_GBF   (2*SEQ*DIM/2)
#define WS_FLOATS (OFF_GBF + SZ_GBF)        // ~21.1 MB

typedef __attribute__((ext_vector_type(8))) short short8;
typedef __attribute__((ext_vector_type(4))) float f32x4;

__device__ __forceinline__ ushort f2bf(float f) {
    union { float f; unsigned u; } v; v.f = f;
    unsigned u = v.u;
    return (ushort)((u + 0x7FFFu + ((u >> 16) & 1u)) >> 16);
}

__device__ __forceinline__ void gload16(void* lds, const void* g) {
    __builtin_amdgcn_global_load_lds(
        (const __attribute__((address_space(1))) unsigned int*)g,
        (__attribute__((address_space(3))) unsigned int*)lds,
        16, 0, 0);
}

// ---------------- fused prep: zero (Kb, vec..sc) + Bbf = bf16(M+M^T) + Qbf/Sbf cvt ----------------
#define ZBLK1 441                 // 451584 / 1024 floats per block
#define ZBLK2 44                  // ceil(44048 / 1024)
#define BBLK  1024                // 512*512 / 256
#define CBLK  4096                // 2 * (4096*512 / 4 / 256)
#define PREP_BLOCKS (ZBLK1 + ZBLK2 + BBLK + CBLK)

__global__ void kprep(const float* __restrict__ M, const float* __restrict__ Q,
                      const float* __restrict__ S, float* __restrict__ ws) {
    int b = blockIdx.x, tid = threadIdx.x;
    if (b < ZBLK1) {
        *reinterpret_cast<float4*>(&ws[OFF_KB + (size_t)(b*256 + tid)*4]) =
            (float4){0.f, 0.f, 0.f, 0.f};
    } else if (b < ZBLK1 + ZBLK2) {
        int i = ((b - ZBLK1)*256 + tid)*4;
        if (i < OFF_BBF - OFF_VEC)
            *reinterpret_cast<float4*>(&ws[OFF_VEC + i]) = (float4){0.f, 0.f, 0.f, 0.f};
    } else if (b < ZBLK1 + ZBLK2 + BBLK) {
        int idx = (b - (ZBLK1 + ZBLK2))*256 + tid;
        int d = idx >> 9, e = idx & 511;
        ((ushort*)(ws + OFF_BBF))[idx] = f2bf(M[d*DIM + e] + M[e*DIM + d]);
    } else {
        int cb = b - (ZBLK1 + ZBLK2 + BBLK);
        int g = cb >> 11;
        const float* src = g ? S : Q;
        size_t idx = ((size_t)(cb & 2047)*256 + tid)*4;
        float4 v = *reinterpret_cast<const float4*>(&src[idx]);
        ushort4 o;
        o.x = f2bf(v.x); o.y = f2bf(v.y); o.z = f2bf(v.z); o.w = f2bf(v.w);
        *reinterpret_cast<ushort4*>(((ushort*)(ws + OFF_QBF)) + (size_t)g*SEQ*DIM + idx) = o;
    }
}

// ---------------- MFMA GEMM, 2-phase pipelined (unchanged from round 3, verified) ----------------
__launch_bounds__(256, 2)
__global__ void kgemm3(const float* __restrict__ P, const float* __restrict__ Q,
                       const float* __restrict__ R, const float* __restrict__ S,
                       const ushort* __restrict__ Bbf, ushort* __restrict__ GBbf,
                       float* __restrict__ pX) {
    int z = blockIdx.z;
    const float* X = (z==0) ? P : (z==1) ? Q : (z==2) ? R : S;
    int i0 = blockIdx.x * 128;
    int j0 = blockIdx.y * 128;
    __shared__ float  As[2*128*32];    // 2 x 16KB, rows 128B, chunk^=(row&7)
    __shared__ ushort Bs[2*128*32];    // 2 x 8KB,  rows 64B,  chunk^=(col&3)
    int tid = threadIdx.x, wv = tid >> 6, l = tid & 63;
    int h = l >> 4, lr = l & 15;
    int wrow = (wv >> 1) * 64, wcol = (wv & 1) * 64;

    auto stage = [&](int buf, int kc) {
        #pragma unroll
        for (int s2 = 0; s2 < 4; ++s2) {          // A: 16 segs of 1KB, 4/wave
            int seg = wv*4 + s2;
            int row = seg*8 + (l >> 3);
            int cs = (l & 7) ^ (row & 7);
            gload16((char*)As + (size_t)buf*16384 + seg*1024,
                    &X[(size_t)(i0+row)*DIM + kc + cs*4]);
        }
        #pragma unroll
        for (int s2 = 0; s2 < 2; ++s2) {          // B: 8 segs of 1KB, 2/wave
            int seg = wv*2 + s2;
            int col = seg*16 + (l >> 2);
            int cs = (l & 3) ^ (col & 3);
            gload16((char*)Bs + (size_t)buf*8192 + seg*1024,
                    &Bbf[(size_t)(j0+col)*DIM + kc + cs*8]);
        }
    };

    f32x4 acc[4][4];
    #pragma unroll
    for (int a = 0; a < 4; ++a)
        #pragma unroll
        for (int b = 0; b < 4; ++b) acc[a][b] = (f32x4){0.f,0.f,0.f,0.f};

    stage(0, 0);
    __syncthreads();
    for (int t = 0; t < 16; ++t) {
        int cur = t & 1;
        if (t < 15) stage(cur ^ 1, (t+1)*32);
        short8 a8[4], b8[4];
        #pragma unroll
        for (int rt = 0; rt < 4; ++rt) {
            int row = wrow + rt*16 + lr;
            const char* base = (const char*)As + (size_t)cur*16384 + row*128;
            int c1 = (2*h)     ^ (row & 7);
            int c2 = (2*h + 1) ^ (row & 7);
            float4 fa = *reinterpret_cast<const float4*>(base + c1*16);
            float4 fb = *reinterpret_cast<const float4*>(base + c2*16);
            short8 tt;
            tt[0]=(short)f2bf(fa.x); tt[1]=(short)f2bf(fa.y);
            tt[2]=(short)f2bf(fa.z); tt[3]=(short)f2bf(fa.w);
            tt[4]=(short)f2bf(fb.x); tt[5]=(short)f2bf(fb.y);
            tt[6]=(short)f2bf(fb.z); tt[7]=(short)f2bf(fb.w);
            a8[rt] = tt;
        }
        #pragma unroll
        for (int ct = 0; ct < 4; ++ct) {
            int col = wcol + ct*16 + lr;
            int c = h ^ (col & 3);
            b8[ct] = *reinterpret_cast<const short8*>(
                (const char*)Bs + (size_t)cur*8192 + col*64 + c*16);
        }
        #pragma unroll
        for (int rt = 0; rt < 4; ++rt)
            #pragma unroll
            for (int ct = 0; ct < 4; ++ct)
                acc[rt][ct] = __builtin_amdgcn_mfma_f32_16x16x32_bf16(a8[rt], b8[ct], acc[rt][ct], 0, 0, 0);
        __syncthreads();
    }

    // epilogue: rowdot (fp32 X reload, coalesced) + GBbf store for z even
    #pragma unroll
    for (int rt = 0; rt < 4; ++rt) {
        #pragma unroll
        for (int r = 0; r < 4; ++r) {
            int row = wrow + rt*16 + h*4 + r;
            float v = 0.f;
            #pragma unroll
            for (int ct = 0; ct < 4; ++ct) {
                int col = wcol + ct*16 + lr;
                float cv = acc[rt][ct][r];
                float xv = X[(size_t)(i0+row)*DIM + j0 + col];
                v = fmaf(cv, xv, v);
                if ((z & 1) == 0)
                    GBbf[((size_t)((z>>1)*SEQ + i0 + row))*DIM + j0 + col] = f2bf(cv);
            }
            v += __shfl_xor(v, 1); v += __shfl_xor(v, 2);
            v += __shfl_xor(v, 4); v += __shfl_xor(v, 8);
            if (lr == 0) atomicAdd(&pX[(size_t)z*SEQ + i0 + row], 0.5f*v);
        }
    }
}

// ---------------- band via MFMA (unchanged from round 3, verified) ----------------
__launch_bounds__(64)
__global__ void kband2(const ushort* __restrict__ GBbf, const ushort* __restrict__ Qbf,
                       const float* __restrict__ pX,
                       float* __restrict__ Kb, float* __restrict__ Db) {
    int g = blockIdx.y;
    int i0 = blockIdx.x * 16;
    int l = threadIdx.x;
    const ushort* A = GBbf + (size_t)g*SEQ*DIM;
    const ushort* Y = Qbf  + (size_t)g*SEQ*DIM;
    const float* pM = pX + (size_t)(2*g)*SEQ;
    const float* qM = pX + (size_t)(2*g+1)*SEQ;
    float* Kbg = Kb + (size_t)g*NDIAG*VSTR;
    float* Dbg = Db + (size_t)g*NDIAG*VSTR;
    int jbase = i0 - BW;
    int arow = i0 + (l & 15);
    int koff = (l >> 4) * 8;
    int jcl[4];
    #pragma unroll
    for (int ct = 0; ct < 4; ++ct) {
        int j = jbase + ct*16 + (l & 15);
        jcl[ct] = min(max(j, 0), SEQ-1);
    }
    f32x4 acc[4];
    #pragma unroll
    for (int ct = 0; ct < 4; ++ct) acc[ct] = (f32x4){0.f,0.f,0.f,0.f};
    #pragma unroll
    for (int ks = 0; ks < 16; ++ks) {
        int kk = ks*32 + koff;
        short8 af = *reinterpret_cast<const short8*>(&A[(size_t)arow*DIM + kk]);
        #pragma unroll
        for (int ct = 0; ct < 4; ++ct) {
            short8 bf = *reinterpret_cast<const short8*>(&Y[(size_t)jcl[ct]*DIM + kk]);
            acc[ct] = __builtin_amdgcn_mfma_f32_16x16x32_bf16(af, bf, acc[ct], 0, 0, 0);
        }
    }
    #pragma unroll
    for (int ct = 0; ct < 4; ++ct) {
        #pragma unroll
        for (int r = 0; r < 4; ++r) {
            int i = i0 + (l >> 4)*4 + r;
            int j = jbase + ct*16 + (l & 15);
            int d = j - i;
            if (d >= -BW && d <= BW && j >= 0 && j < SEQ) {
                float dist = pM[i] + qM[j] - acc[ct][r];
                float fd = (float)d;
                float rel = fd * (1.0f/4096.0f);
                float cd = -0.91893853f - 0.25f*fd*fd + 1e-4f/(rel*rel + 1.0f);
                float Kv = expf(cd - dist*1e-3f);
                Dbg[(size_t)(d + BW)*VSTR + VOFF + i] = dist;
                Kbg[(size_t)(d + BW)*VSTR + VOFF + i] = Kv;
            }
        }
    }
}

// ---------------- Sinkhorn: fused banded matvec chain, 512 rows/block ----------------
// Same verified 42-step schedule as round 3, now in 2 launches (A=5 steps, B=37 steps).
// Out-of-range rows are exactly zero -> skip their matvec entirely (no OOB Kb reads;
// valid rows only touch the +-24 zeroed band pads).
#define SROWS 512
__launch_bounds__(512)
__global__ void ksink2(const float* __restrict__ Kb, float* __restrict__ vecs,
                       float* __restrict__ sc,
                       int nsteps, int firstT, int alphaInit,
                       int vstep, int ustep, int cstep, int gated, int inSlot, int outSlot) {
    int g = blockIdx.y;
    if (gated && sc[g] < 1e-5f) return;   // early-converged: freeze u,v
    const float* Kbg = Kb + (size_t)g * NDIAG * VSTR;
    int r0 = blockIdx.x * SROWS;
    int ext = 24 * nsteps;
    __shared__ float bufA[SROWS + 2*24*37];   // 2288 (max nsteps=37)
    __shared__ float bufB[SROWS + 2*24*37];
    __shared__ float vsave[768];              // only used when cstep>=0 (nsteps<=5 path)
    __shared__ float red[512];
    float* bin = bufA;
    float* bout = bufB;
    int base = r0 - ext;
    int range0 = SROWS + 2*ext;
    const float* vin = vecs + (size_t)(inSlot*2 + g) * VSTR;
    for (int L = threadIdx.x; L < range0; L += 512) {
        int gr = base + L;
        float v = 0.f;
        if (gr >= 0 && gr < SEQ)
            v = alphaInit ? (gr+1)*INV_N : vin[VOFF + gr];
        bufA[L] = v;
    }
    __syncthreads();
    float critloc = 0.f;
    for (int m = 0; m < nsteps; ++m) {
        int e = 24 * (nsteps - 1 - m);
        int lo = ext - e;
        int cnt = SROWS + 2*e;
        int typeT = firstT ^ (m & 1);
        for (int t = threadIdx.x; t < cnt; t += 512) {
            int L = lo + t;
            int gr = base + L;
            float o = 0.f;
            if (gr >= 0 && gr < SEQ) {
                float s0 = 0.f, s1 = 0.f;
                if (typeT) {
                    #pragma unroll
                    for (int idx = 0; idx < 48; idx += 2) {
                        s0 = fmaf(Kbg[(size_t)idx*VSTR + VOFF + gr - idx + BW],
                                  bin[L - idx + BW], s0);
                        s1 = fmaf(Kbg[(size_t)(idx+1)*VSTR + VOFF + gr - idx - 1 + BW],
                                  bin[L - idx - 1 + BW], s1);
                    }
                    s0 = fmaf(Kbg[(size_t)48*VSTR + VOFF + gr - 48 + BW],
                              bin[L - 48 + BW], s0);
                } else {
                    #pragma unroll
                    for (int idx = 0; idx < 48; idx += 2) {
                        s0 = fmaf(Kbg[(size_t)idx*VSTR + VOFF + gr],
                                  bin[L + idx - BW], s0);
                        s1 = fmaf(Kbg[(size_t)(idx+1)*VSTR + VOFF + gr],
                                  bin[L + idx + 1 - BW], s1);
                    }
                    s0 = fmaf(Kbg[(size_t)48*VSTR + VOFF + gr],
                              bin[L + 48 - BW], s0);
                }
                float s = s0 + s1;
                float ab = (gr+1) * INV_N;     // alpha == beta (m==n)
                o = ab / s;
                if (m == vstep) {
                    vecs[(size_t)(4 + g)*VSTR + VOFF + gr] = o;      // v slot
                    if (cstep >= 0) vsave[L] = o;
                }
                if (m == ustep)
                    vecs[(size_t)g*VSTR + VOFF + gr] = o;            // u slot
                if (m == cstep)
                    critloc += fabsf(vsave[L] * s - ab);
            }
            bout[L] = o;
        }
        __syncthreads();
        float* tmp = bin; bin = bout; bout = tmp;
    }
    {
        int gr = r0 + threadIdx.x;
        vecs[(size_t)(outSlot*2 + g)*VSTR + VOFF + gr] = bin[ext + threadIdx.x];
    }
    if (cstep >= 0) {
        red[threadIdx.x] = critloc;
        __syncthreads();
        for (int s = 256; s > 0; s >>= 1) {
            if (threadIdx.x < s) red[threadIdx.x] += red[threadIdx.x + s];
            __syncthreads();
        }
        if (threadIdx.x == 0) atomicAdd(&sc[g], red[0]);
    }
}

// ---------------- final: S_g = sum u_i * K[i,j] * v_j * dist[i,j] over band ----------------
__launch_bounds__(256)
__global__ void kfinal(const float* __restrict__ Kb, const float* __restrict__ Db,
                       const float* __restrict__ vecs, float* __restrict__ sc) {
    int g = blockIdx.y;
    int i = blockIdx.x * 256 + threadIdx.x;
    const float* Kbg = Kb + (size_t)g*NDIAG*VSTR;
    const float* Dbg = Db + (size_t)g*NDIAG*VSTR;
    const float* u = vecs + (size_t)g*VSTR + VOFF;
    const float* v = vecs + (size_t)(4 + g)*VSTR + VOFF;
    float ui = u[i];
    float ss = 0.f;
    #pragma unroll
    for (int idx = 0; idx < NDIAG; ++idx) {
        float kv = Kbg[(size_t)idx*VSTR + VOFF + i];
        float dv = Dbg[(size_t)idx*VSTR + VOFF + i];
        float vv = v[i + idx - BW];
        ss += kv * dv * vv;
    }
    ss *= ui;
    __shared__ float red[256];
    red[threadIdx.x] = ss;
    __syncthreads();
    for (int s = 128; s > 0; s >>= 1) {
        if (threadIdx.x < s) red[threadIdx.x] += red[threadIdx.x + s];
        __syncthreads();
    }
    if (threadIdx.x == 0) atomicAdd(&sc[2+g], red[0]);
}

__global__ void kout(const float* __restrict__ sc, float* __restrict__ out) {
    out[0] = sc[2] - sc[3];
}

extern "C" void kernel_launch(void* const* d_in, const int* in_sizes, int n_in,
                              void* d_out, int out_size, void* d_ws, size_t ws_size,
                              hipStream_t stream) {
    const float* P = (const float*)d_in[0];
    const float* Q = (const float*)d_in[1];
    const float* R = (const float*)d_in[2];
    const float* S = (const float*)d_in[3];
    const float* M = (const float*)d_in[4];
    float* ws = (float*)d_ws;
    if (ws_size < (size_t)WS_FLOATS * sizeof(float)) return;

    float*  Kb  = ws + OFF_KB;
    float*  Db  = ws + OFF_DB;
    float*  vec = ws + OFF_VEC;
    float*  pX  = ws + OFF_PX;
    float*  sc  = ws + OFF_SC;
    ushort* Bbf = (ushort*)(ws + OFF_BBF);
    ushort* Qbf = (ushort*)(ws + OFF_QBF);
    ushort* GBbf= (ushort*)(ws + OFF_GBF);

    kprep <<<dim3(PREP_BLOCKS), dim3(256), 0, stream>>>(M, Q, S, ws);
    kgemm3<<<dim3(32, 4, 4),    dim3(256), 0, stream>>>(P, Q, R, S, Bbf, GBbf, pX);
    kband2<<<dim3(256, 2),      dim3(64),  0, stream>>>(GBbf, Qbf, pX, Kb, Db);

    // Sinkhorn: 42 banded matvecs in 2 fused launches. Slots: 0=u, 1=y, 2=v.
    // A: T(alpha), N->u1, T->v2(store v), N->u2(store u), T->crit1 + y out
    ksink2<<<dim3(8,2), dim3(512), 0, stream>>>(Kb, vec, sc,  5, 1, 1,  2,  3,  4, 0, 0, 1);
    // B: 35 remaining body matvecs + check2 (T->v2' at step 35, N->u2' out), gated on crit1
    ksink2<<<dim3(8,2), dim3(512), 0, stream>>>(Kb, vec, sc, 37, 0, 0, 35, -1, -1, 1, 1, 0);

    kfinal<<<dim3(16,2), dim3(256), 0, stream>>>(Kb, Db, vec, sc);
    kout  <<<dim3(1),    dim3(1),   0, stream>>>(sc, (float*)d_out);
}

// Round 5
// 166.091 us; speedup vs baseline: 1.2797x; 1.2797x over previous
//
#include <hip/hip_runtime.h>
#include <math.h>

// Problem constants
#define SEQ   4096
#define DIM   512
#define BW    24            // band half-width: prior underflows fp32 beyond |i-j|~20
#define NDIAG 49            // 2*BW+1
#define VSTR  4608          // padded row stride for band/vectors (4096 + 512)
#define VOFF  256           // data offset inside padded row (zeros on both sides)
#define INV_N (1.0f/4096.0f)

// ws layout in floats
#define OFF_KB   0                          // K band, 2 groups x 49 x VSTR
#define SZ_BAND  (2*NDIAG*VSTR)             // 451584
#define OFF_DB   (OFF_KB + SZ_BAND)         // dist band (NOT zeroed: always gated by Kb==0)
#define OFF_VEC  (OFF_DB + SZ_BAND)         // 6 padded vectors: u(g0,g1), y(g0,g1), v(g0,g1)
#define SZ_VEC   (6*VSTR)
#define OFF_PX   (OFF_VEC + SZ_VEC)         // pMp for P,Q,R,S : 4 x 4096
#define SZ_PX    (4*SEQ)
#define OFF_SC   (OFF_PX + SZ_PX)           // scalars: [0,1]=crit g0/g1, [2,3]=S g0/g1
#define SZ_SC    16
#define OFF_BBF  (OFF_SC + SZ_SC)           // Bsym bf16 512x512
#define SZ_BBF   (DIM*DIM/2)
#define OFF_QBF  (OFF_BBF + SZ_BBF)         // Q,S bf16 2x4096x512
#define SZ_QBF   (2*SEQ*DIM/2)
#define OFF_GBF  (OFF_QBF + SZ_QBF)         // P@B, R@B bf16
#define SZ_GBF   (2*SEQ*DIM/2)
#define WS_FLOATS (OFF_GBF + SZ_GBF)        // ~21.1 MB

typedef __attribute__((ext_vector_type(8))) short short8;
typedef __attribute__((ext_vector_type(4))) float f32x4;

__device__ __forceinline__ ushort f2bf(float f) {
    union { float f; unsigned u; } v; v.f = f;
    unsigned u = v.u;
    return (ushort)((u + 0x7FFFu + ((u >> 16) & 1u)) >> 16);
}

__device__ __forceinline__ void gload16(void* lds, const void* g) {
    __builtin_amdgcn_global_load_lds(
        (const __attribute__((address_space(1))) unsigned int*)g,
        (__attribute__((address_space(3))) unsigned int*)lds,
        16, 0, 0);
}

// ---------------- fused prep: zero (Kb, vec..sc) + Bbf = bf16(M+M^T) + Qbf/Sbf cvt ----------------
#define ZBLK1 441                 // 451584 / 1024 floats per block
#define ZBLK2 44                  // ceil(44048 / 1024)
#define BBLK  1024                // 512*512 / 256
#define CBLK  4096                // 2 * (4096*512 / 4 / 256)
#define PREP_BLOCKS (ZBLK1 + ZBLK2 + BBLK + CBLK)

__global__ void kprep(const float* __restrict__ M, const float* __restrict__ Q,
                      const float* __restrict__ S, float* __restrict__ ws) {
    int b = blockIdx.x, tid = threadIdx.x;
    if (b < ZBLK1) {
        *reinterpret_cast<float4*>(&ws[OFF_KB + (size_t)(b*256 + tid)*4]) =
            (float4){0.f, 0.f, 0.f, 0.f};
    } else if (b < ZBLK1 + ZBLK2) {
        int i = ((b - ZBLK1)*256 + tid)*4;
        if (i < OFF_BBF - OFF_VEC)
            *reinterpret_cast<float4*>(&ws[OFF_VEC + i]) = (float4){0.f, 0.f, 0.f, 0.f};
    } else if (b < ZBLK1 + ZBLK2 + BBLK) {
        int idx = (b - (ZBLK1 + ZBLK2))*256 + tid;
        int d = idx >> 9, e = idx & 511;
        ((ushort*)(ws + OFF_BBF))[idx] = f2bf(M[d*DIM + e] + M[e*DIM + d]);
    } else {
        int cb = b - (ZBLK1 + ZBLK2 + BBLK);
        int g = cb >> 11;
        const float* src = g ? S : Q;
        size_t idx = ((size_t)(cb & 2047)*256 + tid)*4;
        float4 v = *reinterpret_cast<const float4*>(&src[idx]);
        ushort4 o;
        o.x = f2bf(v.x); o.y = f2bf(v.y); o.z = f2bf(v.z); o.w = f2bf(v.w);
        *reinterpret_cast<ushort4*>(((ushort*)(ws + OFF_QBF)) + (size_t)g*SEQ*DIM + idx) = o;
    }
}

// ---------------- MFMA GEMM, 2-phase pipelined (verified) ----------------
__launch_bounds__(256, 2)
__global__ void kgemm3(const float* __restrict__ P, const float* __restrict__ Q,
                       const float* __restrict__ R, const float* __restrict__ S,
                       const ushort* __restrict__ Bbf, ushort* __restrict__ GBbf,
                       float* __restrict__ pX) {
    int z = blockIdx.z;
    const float* X = (z==0) ? P : (z==1) ? Q : (z==2) ? R : S;
    int i0 = blockIdx.x * 128;
    int j0 = blockIdx.y * 128;
    __shared__ float  As[2*128*32];    // 2 x 16KB, rows 128B, chunk^=(row&7)
    __shared__ ushort Bs[2*128*32];    // 2 x 8KB,  rows 64B,  chunk^=(col&3)
    int tid = threadIdx.x, wv = tid >> 6, l = tid & 63;
    int h = l >> 4, lr = l & 15;
    int wrow = (wv >> 1) * 64, wcol = (wv & 1) * 64;

    auto stage = [&](int buf, int kc) {
        #pragma unroll
        for (int s2 = 0; s2 < 4; ++s2) {          // A: 16 segs of 1KB, 4/wave
            int seg = wv*4 + s2;
            int row = seg*8 + (l >> 3);
            int cs = (l & 7) ^ (row & 7);
            gload16((char*)As + (size_t)buf*16384 + seg*1024,
                    &X[(size_t)(i0+row)*DIM + kc + cs*4]);
        }
        #pragma unroll
        for (int s2 = 0; s2 < 2; ++s2) {          // B: 8 segs of 1KB, 2/wave
            int seg = wv*2 + s2;
            int col = seg*16 + (l >> 2);
            int cs = (l & 3) ^ (col & 3);
            gload16((char*)Bs + (size_t)buf*8192 + seg*1024,
                    &Bbf[(size_t)(j0+col)*DIM + kc + cs*8]);
        }
    };

    f32x4 acc[4][4];
    #pragma unroll
    for (int a = 0; a < 4; ++a)
        #pragma unroll
        for (int b = 0; b < 4; ++b) acc[a][b] = (f32x4){0.f,0.f,0.f,0.f};

    stage(0, 0);
    __syncthreads();
    for (int t = 0; t < 16; ++t) {
        int cur = t & 1;
        if (t < 15) stage(cur ^ 1, (t+1)*32);
        short8 a8[4], b8[4];
        #pragma unroll
        for (int rt = 0; rt < 4; ++rt) {
            int row = wrow + rt*16 + lr;
            const char* base = (const char*)As + (size_t)cur*16384 + row*128;
            int c1 = (2*h)     ^ (row & 7);
            int c2 = (2*h + 1) ^ (row & 7);
            float4 fa = *reinterpret_cast<const float4*>(base + c1*16);
            float4 fb = *reinterpret_cast<const float4*>(base + c2*16);
            short8 tt;
            tt[0]=(short)f2bf(fa.x); tt[1]=(short)f2bf(fa.y);
            tt[2]=(short)f2bf(fa.z); tt[3]=(short)f2bf(fa.w);
            tt[4]=(short)f2bf(fb.x); tt[5]=(short)f2bf(fb.y);
            tt[6]=(short)f2bf(fb.z); tt[7]=(short)f2bf(fb.w);
            a8[rt] = tt;
        }
        #pragma unroll
        for (int ct = 0; ct < 4; ++ct) {
            int col = wcol + ct*16 + lr;
            int c = h ^ (col & 3);
            b8[ct] = *reinterpret_cast<const short8*>(
                (const char*)Bs + (size_t)cur*8192 + col*64 + c*16);
        }
        #pragma unroll
        for (int rt = 0; rt < 4; ++rt)
            #pragma unroll
            for (int ct = 0; ct < 4; ++ct)
                acc[rt][ct] = __builtin_amdgcn_mfma_f32_16x16x32_bf16(a8[rt], b8[ct], acc[rt][ct], 0, 0, 0);
        __syncthreads();
    }

    // epilogue: rowdot (fp32 X reload, coalesced) + GBbf store for z even
    #pragma unroll
    for (int rt = 0; rt < 4; ++rt) {
        #pragma unroll
        for (int r = 0; r < 4; ++r) {
            int row = wrow + rt*16 + h*4 + r;
            float v = 0.f;
            #pragma unroll
            for (int ct = 0; ct < 4; ++ct) {
                int col = wcol + ct*16 + lr;
                float cv = acc[rt][ct][r];
                float xv = X[(size_t)(i0+row)*DIM + j0 + col];
                v = fmaf(cv, xv, v);
                if ((z & 1) == 0)
                    GBbf[((size_t)((z>>1)*SEQ + i0 + row))*DIM + j0 + col] = f2bf(cv);
            }
            v += __shfl_xor(v, 1); v += __shfl_xor(v, 2);
            v += __shfl_xor(v, 4); v += __shfl_xor(v, 8);
            if (lr == 0) atomicAdd(&pX[(size_t)z*SEQ + i0 + row], 0.5f*v);
        }
    }
}

// ---------------- band via MFMA (verified) ----------------
__launch_bounds__(64)
__global__ void kband2(const ushort* __restrict__ GBbf, const ushort* __restrict__ Qbf,
                       const float* __restrict__ pX,
                       float* __restrict__ Kb, float* __restrict__ Db) {
    int g = blockIdx.y;
    int i0 = blockIdx.x * 16;
    int l = threadIdx.x;
    const ushort* A = GBbf + (size_t)g*SEQ*DIM;
    const ushort* Y = Qbf  + (size_t)g*SEQ*DIM;
    const float* pM = pX + (size_t)(2*g)*SEQ;
    const float* qM = pX + (size_t)(2*g+1)*SEQ;
    float* Kbg = Kb + (size_t)g*NDIAG*VSTR;
    float* Dbg = Db + (size_t)g*NDIAG*VSTR;
    int jbase = i0 - BW;
    int arow = i0 + (l & 15);
    int koff = (l >> 4) * 8;
    int jcl[4];
    #pragma unroll
    for (int ct = 0; ct < 4; ++ct) {
        int j = jbase + ct*16 + (l & 15);
        jcl[ct] = min(max(j, 0), SEQ-1);
    }
    f32x4 acc[4];
    #pragma unroll
    for (int ct = 0; ct < 4; ++ct) acc[ct] = (f32x4){0.f,0.f,0.f,0.f};
    #pragma unroll
    for (int ks = 0; ks < 16; ++ks) {
        int kk = ks*32 + koff;
        short8 af = *reinterpret_cast<const short8*>(&A[(size_t)arow*DIM + kk]);
        #pragma unroll
        for (int ct = 0; ct < 4; ++ct) {
            short8 bf = *reinterpret_cast<const short8*>(&Y[(size_t)jcl[ct]*DIM + kk]);
            acc[ct] = __builtin_amdgcn_mfma_f32_16x16x32_bf16(af, bf, acc[ct], 0, 0, 0);
        }
    }
    #pragma unroll
    for (int ct = 0; ct < 4; ++ct) {
        #pragma unroll
        for (int r = 0; r < 4; ++r) {
            int i = i0 + (l >> 4)*4 + r;
            int j = jbase + ct*16 + (l & 15);
            int d = j - i;
            if (d >= -BW && d <= BW && j >= 0 && j < SEQ) {
                float dist = pM[i] + qM[j] - acc[ct][r];
                float fd = (float)d;
                float rel = fd * (1.0f/4096.0f);
                float cd = -0.91893853f - 0.25f*fd*fd + 1e-4f/(rel*rel + 1.0f);
                float Kv = expf(cd - dist*1e-3f);
                Dbg[(size_t)(d + BW)*VSTR + VOFF + i] = dist;
                Kbg[(size_t)(d + BW)*VSTR + VOFF + i] = Kv;
            }
        }
    }
}

// ---------------- Sinkhorn: fused banded matvec chain, 256 rows/block, k<=7 ----------------
#define SROWS 256
#define SEXT  (24*7)          // max halo
#define SBUF  (SROWS + 2*SEXT) // 592
__launch_bounds__(256)
__global__ void ksink2(const float* __restrict__ Kb, float* __restrict__ vecs,
                       float* __restrict__ sc,
                       int nsteps, int firstT, int alphaInit,
                       int vstep, int ustep, int cstep, int gated, int inSlot, int outSlot) {
    int g = blockIdx.y;
    if (gated && sc[g] < 1e-5f) return;   // early-converged: freeze u,v
    const float* Kbg = Kb + (size_t)g * NDIAG * VSTR;
    int r0 = blockIdx.x * SROWS;
    int ext = 24 * nsteps;
    __shared__ float bufA[SBUF];
    __shared__ float bufB[SBUF];
    __shared__ float vsave[SBUF];
    __shared__ float red[256];
    float* bin = bufA;
    float* bout = bufB;
    int base = r0 - ext;
    int range0 = SROWS + 2*ext;
    const float* vin = vecs + (size_t)(inSlot*2 + g) * VSTR;
    for (int L = threadIdx.x; L < range0; L += 256) {
        int gr = base + L;
        float v = 0.f;
        if (gr >= 0 && gr < SEQ)
            v = alphaInit ? (gr+1)*INV_N : vin[VOFF + gr];
        bufA[L] = v;
    }
    __syncthreads();
    float critloc = 0.f;
    for (int m = 0; m < nsteps; ++m) {
        int e = 24 * (nsteps - 1 - m);
        int lo = ext - e;
        int cnt = SROWS + 2*e;
        int typeT = firstT ^ (m & 1);
        for (int t = threadIdx.x; t < cnt; t += 256) {
            int L = lo + t;
            int gr = base + L;
            float o = 0.f;
            if (gr >= 0 && gr < SEQ) {
                float s0 = 0.f, s1 = 0.f;
                if (typeT) {
                    #pragma unroll
                    for (int idx = 0; idx < 48; idx += 2) {
                        s0 = fmaf(Kbg[(size_t)idx*VSTR + VOFF + gr - idx + BW],
                                  bin[L - idx + BW], s0);
                        s1 = fmaf(Kbg[(size_t)(idx+1)*VSTR + VOFF + gr - idx - 1 + BW],
                                  bin[L - idx - 1 + BW], s1);
                    }
                    s0 = fmaf(Kbg[(size_t)48*VSTR + VOFF + gr - 48 + BW],
                              bin[L - 48 + BW], s0);
                } else {
                    #pragma unroll
                    for (int idx = 0; idx < 48; idx += 2) {
                        s0 = fmaf(Kbg[(size_t)idx*VSTR + VOFF + gr],
                                  bin[L + idx - BW], s0);
                        s1 = fmaf(Kbg[(size_t)(idx+1)*VSTR + VOFF + gr],
                                  bin[L + idx + 1 - BW], s1);
                    }
                    s0 = fmaf(Kbg[(size_t)48*VSTR + VOFF + gr],
                              bin[L + 48 - BW], s0);
                }
                float s = s0 + s1;
                float ab = (gr+1) * INV_N;     // alpha == beta (m==n)
                o = ab / s;
                if (m == vstep) {
                    vecs[(size_t)(4 + g)*VSTR + VOFF + gr] = o;      // v slot
                    if (cstep >= 0) vsave[L] = o;
                }
                if (m == ustep)
                    vecs[(size_t)g*VSTR + VOFF + gr] = o;            // u slot
                if (m == cstep)
                    critloc += fabsf(vsave[L] * s - ab);
            }
            bout[L] = o;
        }
        __syncthreads();
        float* tmp = bin; bin = bout; bout = tmp;
    }
    {
        int gr = r0 + threadIdx.x;
        vecs[(size_t)(outSlot*2 + g)*VSTR + VOFF + gr] = bin[ext + threadIdx.x];
    }
    if (cstep >= 0) {
        red[threadIdx.x] = critloc;
        __syncthreads();
        for (int s = 128; s > 0; s >>= 1) {
            if (threadIdx.x < s) red[threadIdx.x] += red[threadIdx.x + s];
            __syncthreads();
        }
        if (threadIdx.x == 0) atomicAdd(&sc[g], red[0]);
    }
}

// ---------------- final: S_g = sum u_i * K[i,j] * v_j * dist[i,j] over band ----------------
__launch_bounds__(256)
__global__ void kfinal(const float* __restrict__ Kb, const float* __restrict__ Db,
                       const float* __restrict__ vecs, float* __restrict__ sc) {
    int g = blockIdx.y;
    int i = blockIdx.x * 256 + threadIdx.x;
    const float* Kbg = Kb + (size_t)g*NDIAG*VSTR;
    const float* Dbg = Db + (size_t)g*NDIAG*VSTR;
    const float* u = vecs + (size_t)g*VSTR + VOFF;
    const float* v = vecs + (size_t)(4 + g)*VSTR + VOFF;
    float ui = u[i];
    float ss = 0.f;
    #pragma unroll
    for (int idx = 0; idx < NDIAG; ++idx) {
        float kv = Kbg[(size_t)idx*VSTR + VOFF + i];
        float dv = Dbg[(size_t)idx*VSTR + VOFF + i];
        float vv = v[i + idx - BW];
        ss += kv * dv * vv;
    }
    ss *= ui;
    __shared__ float red[256];
    red[threadIdx.x] = ss;
    __syncthreads();
    for (int s = 128; s > 0; s >>= 1) {
        if (threadIdx.x < s) red[threadIdx.x] += red[threadIdx.x + s];
        __syncthreads();
    }
    if (threadIdx.x == 0) atomicAdd(&sc[2+g], red[0]);
}

__global__ void kout(const float* __restrict__ sc, float* __restrict__ out) {
    out[0] = sc[2] - sc[3];
}

extern "C" void kernel_launch(void* const* d_in, const int* in_sizes, int n_in,
                              void* d_out, int out_size, void* d_ws, size_t ws_size,
                              hipStream_t stream) {
    const float* P = (const float*)d_in[0];
    const float* Q = (const float*)d_in[1];
    const float* R = (const float*)d_in[2];
    const float* S = (const float*)d_in[3];
    const float* M = (const float*)d_in[4];
    float* ws = (float*)d_ws;
    if (ws_size < (size_t)WS_FLOATS * sizeof(float)) return;

    float*  Kb  = ws + OFF_KB;
    float*  Db  = ws + OFF_DB;
    float*  vec = ws + OFF_VEC;
    float*  pX  = ws + OFF_PX;
    float*  sc  = ws + OFF_SC;
    ushort* Bbf = (ushort*)(ws + OFF_BBF);
    ushort* Qbf = (ushort*)(ws + OFF_QBF);
    ushort* GBbf= (ushort*)(ws + OFF_GBF);

    kprep <<<dim3(PREP_BLOCKS), dim3(256), 0, stream>>>(M, Q, S, ws);
    kgemm3<<<dim3(32, 4, 4),    dim3(256), 0, stream>>>(P, Q, R, S, Bbf, GBbf, pX);
    kband2<<<dim3(256, 2),      dim3(64),  0, stream>>>(GBbf, Qbf, pX, Kb, Db);

    // Sinkhorn: 42 banded matvecs in 8 fused launches. Slots: 0=u, 1=y, 2=v.
    // A: T(alpha), N->u1, T->v2(store v), N->u2(store u), T->crit1 + y out (slot1)
    ksink2<<<dim3(16,2), dim3(256), 0, stream>>>(Kb, vec, sc,  5, 1, 1,  2,  3,  4, 0, 0, 1);
    // bodies: 5 x 6 steps (N,T alternating), gated on crit1
    ksink2<<<dim3(16,2), dim3(256), 0, stream>>>(Kb, vec, sc,  6, 0, 0, -1, -1, -1, 1, 1, 1);
    ksink2<<<dim3(16,2), dim3(256), 0, stream>>>(Kb, vec, sc,  6, 0, 0, -1, -1, -1, 1, 1, 1);
    ksink2<<<dim3(16,2), dim3(256), 0, stream>>>(Kb, vec, sc,  6, 0, 0, -1, -1, -1, 1, 1, 1);
    ksink2<<<dim3(16,2), dim3(256), 0, stream>>>(Kb, vec, sc,  6, 0, 0, -1, -1, -1, 1, 1, 1);
    ksink2<<<dim3(16,2), dim3(256), 0, stream>>>(Kb, vec, sc,  6, 0, 0, -1, -1, -1, 1, 1, 1);
    // last: 7 steps incl. check2 (T->v2' at local m=5, N->u2' out slot0)
    ksink2<<<dim3(16,2), dim3(256), 0, stream>>>(Kb, vec, sc,  7, 0, 0,  5, -1, -1, 1, 1, 0);

    kfinal<<<dim3(16,2), dim3(256), 0, stream>>>(Kb, Db, vec, sc);
    kout  <<<dim3(1),    dim3(1),   0, stream>>>(sc, (float*)d_out);
}

// Round 6
// 159.611 us; speedup vs baseline: 1.3316x; 1.0406x over previous
//
#include <hip/hip_runtime.h>
#include <hip/hip_bf16.h>
#include <math.h>

// Problem constants
#define SEQ   4096
#define DIM   512
#define BW    24            // band half-width: prior underflows fp32 beyond |i-j|~20
#define NDIAG 49            // 2*BW+1
#define TW    56            // padded tap width (49 -> 56 for 16B alignment)
#define VSTR  4608          // padded row stride for vectors (4096 + 512)
#define VOFF  256           // data offset inside padded row (zeros on both sides)
#define INV_N (1.0f/4096.0f)

// ws layout in floats (21.15 MB total; r1's 21.61 MB fit, so safe)
#define OFF_KT   0                          // Kt bf16 [2][4096][56]: taps for N-step
#define SZ_KT    (2*SEQ*TW/2)               // 229376
#define OFF_KC   (OFF_KT + SZ_KT)           // Kc bf16 [2][4096][56]: taps for T-step
#define SZ_KC    (2*SEQ*TW/2)               // 229376
#define OFF_DT   (OFF_KC + SZ_KC)           // Dt fp32 [2][4096][56]
#define SZ_DT    (2*SEQ*TW)                 // 458752
#define OFF_VEC  (OFF_DT + SZ_DT)           // 6 padded vectors: u(g0,g1), y(g0,g1), v(g0,g1)
#define SZ_VEC   (6*VSTR)
#define OFF_PX   (OFF_VEC + SZ_VEC)         // pMp for P,Q,R,S : 4 x 4096
#define SZ_PX    (4*SEQ)
#define OFF_SC   (OFF_PX + SZ_PX)           // scalars: [0,1]=crit g0/g1, [2,3]=S g0/g1
#define SZ_SC    16
#define OFF_BBF  (OFF_SC + SZ_SC)           // Bsym bf16 512x512
#define SZ_BBF   (DIM*DIM/2)
#define OFF_QBF  (OFF_BBF + SZ_BBF)         // Q,S bf16 2x4096x512
#define SZ_QBF   (2*SEQ*DIM/2)
#define OFF_GBF  (OFF_QBF + SZ_QBF)         // P@B, R@B bf16
#define SZ_GBF   (2*SEQ*DIM/2)
#define WS_FLOATS (OFF_GBF + SZ_GBF)        // 5,286,928 floats

typedef __attribute__((ext_vector_type(8))) short short8;
typedef __attribute__((ext_vector_type(8))) unsigned short ushort8;
typedef __attribute__((ext_vector_type(4))) float f32x4;

__device__ __forceinline__ ushort f2bfh(float f) {
    __hip_bfloat16 h = __float2bfloat16(f);      // native v_cvt (RNE)
    return *reinterpret_cast<ushort*>(&h);
}
__device__ __forceinline__ float bf2f(ushort u) {
    union { unsigned u; float f; } w; w.u = ((unsigned)u) << 16; return w.f;
}

__device__ __forceinline__ void gload16(void* lds, const void* g) {
    __builtin_amdgcn_global_load_lds(
        (const __attribute__((address_space(1))) unsigned int*)g,
        (__attribute__((address_space(3))) unsigned int*)lds,
        16, 0, 0);
}

// ---------------- fused prep: zero bands+vec+pX+sc, Bbf = bf16(M+M^T), Qbf/Sbf cvt ----------------
#define ZQUADS (OFF_BBF/4)                  // 240388 float4 zeros
#define ZBLK   ((ZQUADS + 255)/256)         // 940
#define BBLK   1024
#define CBLK   4096
#define PREP_BLOCKS (ZBLK + BBLK + CBLK)

__global__ void kprep(const float* __restrict__ M, const float* __restrict__ Q,
                      const float* __restrict__ S, float* __restrict__ ws) {
    int b = blockIdx.x, tid = threadIdx.x;
    if (b < ZBLK) {
        int q = b*256 + tid;
        if (q < ZQUADS)
            *reinterpret_cast<float4*>(&ws[(size_t)q*4]) = (float4){0.f,0.f,0.f,0.f};
    } else if (b < ZBLK + BBLK) {
        int idx = (b - ZBLK)*256 + tid;
        int d = idx >> 9, e = idx & 511;
        ((ushort*)(ws + OFF_BBF))[idx] = f2bfh(M[d*DIM + e] + M[e*DIM + d]);
    } else {
        int cb = b - (ZBLK + BBLK);
        int g = cb >> 11;
        const float* src = g ? S : Q;
        size_t idx = ((size_t)(cb & 2047)*256 + tid)*4;
        float4 v = *reinterpret_cast<const float4*>(&src[idx]);
        ushort4 o;
        o.x = f2bfh(v.x); o.y = f2bfh(v.y); o.z = f2bfh(v.z); o.w = f2bfh(v.w);
        *reinterpret_cast<ushort4*>(((ushort*)(ws + OFF_QBF)) + (size_t)g*SEQ*DIM + idx) = o;
    }
}

// ---------------- MFMA GEMM: z=0,2 -> fp32 A (P,R) + native cvt; z=1,3 -> bf16 A (Qbf) ----------------
__launch_bounds__(256, 2)
__global__ void kgemm4(const float* __restrict__ P, const float* __restrict__ R,
                       const ushort* __restrict__ Qbf, const ushort* __restrict__ Bbf,
                       ushort* __restrict__ GBbf, float* __restrict__ pX) {
    int z = blockIdx.z;
    int abf = z & 1;
    const float*  Xf = (z == 0) ? P : R;
    const ushort* Xh = Qbf + (size_t)(z >> 1)*SEQ*DIM;
    int i0 = blockIdx.x * 128;
    int j0 = blockIdx.y * 128;
    __shared__ float  As[2*128*32];    // fp32 path: 2x16KB (rows 128B, chunk^=(row&7)); bf16 path: 2x8KB chunk-major
    __shared__ ushort Bs[2*128*32];    // 2x8KB, rows 64B, chunk^=(col&3)
    int tid = threadIdx.x, wv = tid >> 6, l = tid & 63;
    int h = l >> 4, lr = l & 15;
    int wrow = (wv >> 1)*64, wcol = (wv & 1)*64;

    auto stageB = [&](int buf, int kc) {
        #pragma unroll
        for (int s2 = 0; s2 < 2; ++s2) {
            int seg = wv*2 + s2;
            int col = seg*16 + (l >> 2);
            int cs = (l & 3) ^ (col & 3);
            gload16((char*)Bs + (size_t)buf*8192 + seg*1024,
                    &Bbf[(size_t)(j0+col)*DIM + kc + cs*8]);
        }
    };
    auto stageAf = [&](int buf, int kc) {
        #pragma unroll
        for (int s2 = 0; s2 < 4; ++s2) {
            int seg = wv*4 + s2;
            int row = seg*8 + (l >> 3);
            int cs = (l & 7) ^ (row & 7);
            gload16((char*)As + (size_t)buf*16384 + seg*1024,
                    &Xf[(size_t)(i0+row)*DIM + kc + cs*4]);
        }
    };
    auto stageAh = [&](int buf, int kc) {
        #pragma unroll
        for (int s2 = 0; s2 < 2; ++s2) {
            int seg = wv*2 + s2;                           // 8 segs: chunk=seg>>1, rowhalf=seg&1
            gload16((char*)As + (size_t)buf*8192 + seg*1024,
                    &Xh[(size_t)(i0 + (seg&1)*64 + l)*DIM + kc + (seg>>1)*8]);
        }
    };

    f32x4 acc[4][4];
    #pragma unroll
    for (int a = 0; a < 4; ++a)
        #pragma unroll
        for (int b = 0; b < 4; ++b) acc[a][b] = (f32x4){0.f,0.f,0.f,0.f};

    if (abf) stageAh(0, 0); else stageAf(0, 0);
    stageB(0, 0);
    __syncthreads();
    for (int t = 0; t < 16; ++t) {
        int cur = t & 1;
        if (t < 15) {
            if (abf) stageAh(cur ^ 1, (t+1)*32); else stageAf(cur ^ 1, (t+1)*32);
            stageB(cur ^ 1, (t+1)*32);
        }
        short8 a8[4], b8[4];
        if (abf) {
            #pragma unroll
            for (int rt = 0; rt < 4; ++rt) {
                int row = wrow + rt*16 + lr;
                a8[rt] = *reinterpret_cast<const short8*>(
                    (const char*)As + (size_t)cur*8192 + h*2048 + row*16);
            }
        } else {
            #pragma unroll
            for (int rt = 0; rt < 4; ++rt) {
                int row = wrow + rt*16 + lr;
                const char* base = (const char*)As + (size_t)cur*16384 + row*128;
                int c1 = (2*h)     ^ (row & 7);
                int c2 = (2*h + 1) ^ (row & 7);
                float4 fa = *reinterpret_cast<const float4*>(base + c1*16);
                float4 fb = *reinterpret_cast<const float4*>(base + c2*16);
                short8 tt;
                tt[0]=(short)f2bfh(fa.x); tt[1]=(short)f2bfh(fa.y);
                tt[2]=(short)f2bfh(fa.z); tt[3]=(short)f2bfh(fa.w);
                tt[4]=(short)f2bfh(fb.x); tt[5]=(short)f2bfh(fb.y);
                tt[6]=(short)f2bfh(fb.z); tt[7]=(short)f2bfh(fb.w);
                a8[rt] = tt;
            }
        }
        #pragma unroll
        for (int ct = 0; ct < 4; ++ct) {
            int col = wcol + ct*16 + lr;
            int c = h ^ (col & 3);
            b8[ct] = *reinterpret_cast<const short8*>(
                (const char*)Bs + (size_t)cur*8192 + col*64 + c*16);
        }
        #pragma unroll
        for (int rt = 0; rt < 4; ++rt)
            #pragma unroll
            for (int ct = 0; ct < 4; ++ct)
                acc[rt][ct] = __builtin_amdgcn_mfma_f32_16x16x32_bf16(a8[rt], b8[ct], acc[rt][ct], 0, 0, 0);
        __syncthreads();
    }

    // epilogue: rowdot + GBbf store (fp32 path only)
    #pragma unroll
    for (int rt = 0; rt < 4; ++rt) {
        #pragma unroll
        for (int r = 0; r < 4; ++r) {
            int row = wrow + rt*16 + h*4 + r;
            float v = 0.f;
            #pragma unroll
            for (int ct = 0; ct < 4; ++ct) {
                int col = wcol + ct*16 + lr;
                float cv = acc[rt][ct][r];
                float xv;
                if (abf) xv = bf2f(Xh[(size_t)(i0+row)*DIM + j0 + col]);
                else     xv = Xf[(size_t)(i0+row)*DIM + j0 + col];
                v = fmaf(cv, xv, v);
                if (!abf)
                    GBbf[((size_t)((z>>1)*SEQ + i0 + row))*DIM + j0 + col] = f2bfh(cv);
            }
            v += __shfl_xor(v, 1); v += __shfl_xor(v, 2);
            v += __shfl_xor(v, 4); v += __shfl_xor(v, 8);
            if (lr == 0) atomicAdd(&pX[(size_t)z*SEQ + i0 + row], 0.5f*v);
        }
    }
}

// ---------------- band via MFMA -> row-major taps Kt/Kc (bf16) + Dt (fp32) ----------------
__launch_bounds__(64)
__global__ void kband3(const ushort* __restrict__ GBbf, const ushort* __restrict__ Qbf,
                       const float* __restrict__ pX,
                       ushort* __restrict__ Ktb, ushort* __restrict__ Kcb,
                       float* __restrict__ Dt) {
    int g = blockIdx.y;
    int i0 = blockIdx.x * 16;
    int l = threadIdx.x;
    const ushort* A = GBbf + (size_t)g*SEQ*DIM;
    const ushort* Y = Qbf  + (size_t)g*SEQ*DIM;
    const float* pM = pX + (size_t)(2*g)*SEQ;
    const float* qM = pX + (size_t)(2*g+1)*SEQ;
    int jbase = i0 - BW;
    int arow = i0 + (l & 15);
    int koff = (l >> 4) * 8;
    int jcl[4];
    #pragma unroll
    for (int ct = 0; ct < 4; ++ct) {
        int j = jbase + ct*16 + (l & 15);
        jcl[ct] = min(max(j, 0), SEQ-1);
    }
    f32x4 acc[4];
    #pragma unroll
    for (int ct = 0; ct < 4; ++ct) acc[ct] = (f32x4){0.f,0.f,0.f,0.f};
    #pragma unroll
    for (int ks = 0; ks < 16; ++ks) {
        int kk = ks*32 + koff;
        short8 af = *reinterpret_cast<const short8*>(&A[(size_t)arow*DIM + kk]);
        #pragma unroll
        for (int ct = 0; ct < 4; ++ct) {
            short8 bf = *reinterpret_cast<const short8*>(&Y[(size_t)jcl[ct]*DIM + kk]);
            acc[ct] = __builtin_amdgcn_mfma_f32_16x16x32_bf16(af, bf, acc[ct], 0, 0, 0);
        }
    }
    #pragma unroll
    for (int ct = 0; ct < 4; ++ct) {
        #pragma unroll
        for (int r = 0; r < 4; ++r) {
            int i = i0 + (l >> 4)*4 + r;
            int j = jbase + ct*16 + (l & 15);
            int d = j - i;
            if (d >= -BW && d <= BW && j >= 0 && j < SEQ) {
                float dist = pM[i] + qM[j] - acc[ct][r];
                float fd = (float)d;
                float rel = fd * (1.0f/4096.0f);
                float cd = -0.91893853f - 0.25f*fd*fd + 1e-4f/(rel*rel + 1.0f);
                float Kv = expf(cd - dist*1e-3f);
                ushort kvu = f2bfh(Kv);
                Ktb[((size_t)g*SEQ + i)*TW + (d + BW)] = kvu;
                Kcb[((size_t)g*SEQ + j)*TW + (BW - d)] = kvu;
                Dt [((size_t)g*SEQ + i)*TW + (d + BW)] = dist;
            }
        }
    }
}

// ---------------- Sinkhorn: fused banded matvec chain, row-major bf16 taps ----------------
// N-step: out[i] = a_i / sum_t Kt[i][t]*in[i+t-BW];  T-step: same form with Kc.
#define SR3  64
#define SB3  416          // >= range0(400 max) + 16 headroom; tap pads (49..55) are zero
__launch_bounds__(256)
__global__ void ksink3(const ushort* __restrict__ Ktb, const ushort* __restrict__ Kcb,
                       float* __restrict__ vecs, float* __restrict__ sc,
                       int nsteps, int firstT, int alphaInit,
                       int vstep, int ustep, int cstep, int gated, int inSlot, int outSlot) {
    int g = blockIdx.y;
    if (gated && sc[g] < 1e-5f) return;   // early-converged: freeze u,v
    int r0 = blockIdx.x * SR3;
    int ext = 24 * nsteps;
    __shared__ float bufA[SB3];
    __shared__ float bufB[SB3];
    __shared__ float vsave[SB3];
    __shared__ float red[256];
    float* bin = bufA;
    float* bout = bufB;
    int base = r0 - ext;
    int range0 = SR3 + 2*ext;
    const float* vin = vecs + (size_t)(inSlot*2 + g)*VSTR;
    for (int L = threadIdx.x; L < SB3; L += 256) {
        int gr = base + L;
        float v = 0.f;
        if (L < range0 && gr >= 0 && gr < SEQ)
            v = alphaInit ? (gr+1)*INV_N : vin[VOFF + gr];
        bufA[L] = v;
        bufB[L] = 0.f;
    }
    __syncthreads();
    float critloc = 0.f;
    for (int m = 0; m < nsteps; ++m) {
        int e = 24*(nsteps - 1 - m);
        int lo = ext - e;
        int cnt = SR3 + 2*e;
        int typeT = firstT ^ (m & 1);
        const ushort* tap0 = (typeT ? Kcb : Ktb) + (size_t)g*SEQ*TW;
        for (int t = threadIdx.x; t < cnt; t += 256) {
            int L = lo + t;
            int gr = base + L;
            float o = 0.f;
            if (gr >= 0 && gr < SEQ) {
                const ushort* tap = tap0 + (size_t)gr*TW;
                float s = 0.f;
                #pragma unroll
                for (int c = 0; c < 7; ++c) {
                    ushort8 k8 = *reinterpret_cast<const ushort8*>(tap + c*8);
                    #pragma unroll
                    for (int ee = 0; ee < 8; ++ee)
                        s = fmaf(bf2f(k8[ee]), bin[L + c*8 + ee - BW], s);
                }
                float ab = (gr+1)*INV_N;      // alpha == beta (m==n)
                o = ab / s;
                if (m == vstep) {
                    vecs[(size_t)(4 + g)*VSTR + VOFF + gr] = o;      // v slot
                    if (cstep >= 0) vsave[L] = o;
                }
                if (m == ustep)
                    vecs[(size_t)g*VSTR + VOFF + gr] = o;            // u slot
                if (m == cstep)
                    critloc += fabsf(vsave[L]*s - ab);
            }
            bout[L] = o;
        }
        __syncthreads();
        float* tmp = bin; bin = bout; bout = tmp;
    }
    if (threadIdx.x < SR3) {
        int gr = r0 + threadIdx.x;
        vecs[(size_t)(outSlot*2 + g)*VSTR + VOFF + gr] = bin[ext + threadIdx.x];
    }
    if (cstep >= 0) {
        red[threadIdx.x] = critloc;
        __syncthreads();
        for (int s = 128; s > 0; s >>= 1) {
            if (threadIdx.x < s) red[threadIdx.x] += red[threadIdx.x + s];
            __syncthreads();
        }
        if (threadIdx.x == 0) atomicAdd(&sc[g], red[0]);
    }
}

// ---------------- final: S_g = sum_i u_i * sum_t Kt[i][t]*Dt[i][t]*v[i+t-BW] ----------------
__launch_bounds__(256)
__global__ void kfinal(const ushort* __restrict__ Ktb, const float* __restrict__ Dt,
                       const float* __restrict__ vecs, float* __restrict__ sc) {
    int g = blockIdx.y;
    int i = blockIdx.x * 256 + threadIdx.x;
    const ushort* kt = Ktb + ((size_t)g*SEQ + i)*TW;
    const float*  dt = Dt  + ((size_t)g*SEQ + i)*TW;
    const float* u = vecs + (size_t)g*VSTR + VOFF;
    const float* v = vecs + (size_t)(4 + g)*VSTR + VOFF;
    float ss = 0.f;
    #pragma unroll
    for (int c = 0; c < 7; ++c) {
        ushort8 k8 = *reinterpret_cast<const ushort8*>(kt + c*8);
        #pragma unroll
        for (int ee = 0; ee < 8; ++ee) {
            int t = c*8 + ee;
            ss += bf2f(k8[ee]) * dt[t] * v[i + t - BW];
        }
    }
    ss *= u[i];
    __shared__ float red[256];
    red[threadIdx.x] = ss;
    __syncthreads();
    for (int s = 128; s > 0; s >>= 1) {
        if (threadIdx.x < s) red[threadIdx.x] += red[threadIdx.x + s];
        __syncthreads();
    }
    if (threadIdx.x == 0) atomicAdd(&sc[2+g], red[0]);
}

__global__ void kout(const float* __restrict__ sc, float* __restrict__ out) {
    out[0] = sc[2] - sc[3];
}

extern "C" void kernel_launch(void* const* d_in, const int* in_sizes, int n_in,
                              void* d_out, int out_size, void* d_ws, size_t ws_size,
                              hipStream_t stream) {
    const float* P = (const float*)d_in[0];
    const float* Q = (const float*)d_in[1];
    const float* R = (const float*)d_in[2];
    const float* S = (const float*)d_in[3];
    const float* M = (const float*)d_in[4];
    float* ws = (float*)d_ws;
    if (ws_size < (size_t)WS_FLOATS * sizeof(float)) return;

    ushort* Ktb = (ushort*)(ws + OFF_KT);
    ushort* Kcb = (ushort*)(ws + OFF_KC);
    float*  Dt  = ws + OFF_DT;
    float*  vec = ws + OFF_VEC;
    float*  pX  = ws + OFF_PX;
    float*  sc  = ws + OFF_SC;
    ushort* Bbf = (ushort*)(ws + OFF_BBF);
    ushort* Qbf = (ushort*)(ws + OFF_QBF);
    ushort* GBbf= (ushort*)(ws + OFF_GBF);

    kprep <<<dim3(PREP_BLOCKS), dim3(256), 0, stream>>>(M, Q, S, ws);
    kgemm4<<<dim3(32, 4, 4),    dim3(256), 0, stream>>>(P, R, Qbf, Bbf, GBbf, pX);
    kband3<<<dim3(256, 2),      dim3(64),  0, stream>>>(GBbf, Qbf, pX, Ktb, Kcb, Dt);

    // Sinkhorn: 42 banded matvecs in 8 fused launches. Slots: 0=u, 1=y, 2=v.
    // A: T(alpha), N->u1, T->v2(store v), N->u2(store u), T->crit1 + y out (slot1)
    ksink3<<<dim3(64,2), dim3(256), 0, stream>>>(Ktb, Kcb, vec, sc,  5, 1, 1,  2,  3,  4, 0, 0, 1);
    // bodies: 5 x 6 steps (N,T alternating), gated on crit1
    ksink3<<<dim3(64,2), dim3(256), 0, stream>>>(Ktb, Kcb, vec, sc,  6, 0, 0, -1, -1, -1, 1, 1, 1);
    ksink3<<<dim3(64,2), dim3(256), 0, stream>>>(Ktb, Kcb, vec, sc,  6, 0, 0, -1, -1, -1, 1, 1, 1);
    ksink3<<<dim3(64,2), dim3(256), 0, stream>>>(Ktb, Kcb, vec, sc,  6, 0, 0, -1, -1, -1, 1, 1, 1);
    ksink3<<<dim3(64,2), dim3(256), 0, stream>>>(Ktb, Kcb, vec, sc,  6, 0, 0, -1, -1, -1, 1, 1, 1);
    ksink3<<<dim3(64,2), dim3(256), 0, stream>>>(Ktb, Kcb, vec, sc,  6, 0, 0, -1, -1, -1, 1, 1, 1);
    // last: 7 steps incl. check2 (T->v2' at local m=5, N->u2' out slot0)
    ksink3<<<dim3(64,2), dim3(256), 0, stream>>>(Ktb, Kcb, vec, sc,  7, 0, 0,  5, -1, -1, 1, 1, 0);

    kfinal<<<dim3(16,2), dim3(256), 0, stream>>>(Ktb, Dt, vec, sc);
    kout  <<<dim3(1),    dim3(1),   0, stream>>>(sc, (float*)d_out);
}